// Round 6
// baseline (139.873 us; speedup 1.0000x reference)
//
#include <hip/hip_runtime.h>
#include <math.h>

#define POOLED      7
#define OUTPUT_DIM  21
#define GROUP       7
#define CHANNELS    (OUTPUT_DIM * GROUP * GROUP)   // 1029
#define FH          64
#define FW          64
#define PLANE       (FH * FW)                      // 4096 floats, 16 KB
#define NUM_ROIS    1024
#define SCALE       0.0625f

// Opaque VGPR pin: blocks FMA contraction (hipcc -ffp-contract=fast ignores
// `#pragma clang fp contract(off)`). CORRECTNESS-CRITICAL: the golden's
// boundary chain is f32, separately rounded, with bin = roi * RN(1/7)
// (reciprocal multiply) — verified round 10, absmax 3.9e-3. Do not change.
__device__ __forceinline__ float freeze(float x) {
    __asm__ volatile("" : "+v"(x));
    return x;
}

// ---- frozen boundary chain, value form (ops identical to r10-verified) ----
struct RoiGeom { int b; float start_h, start_w, bin_h, bin_w; };

__device__ __forceinline__ RoiGeom roi_geom_v(float r0, float r1, float r2,
                                              float r3, float r4) {
    RoiGeom g;
    g.b = (int)r0;
    float start_w = rintf(r1) * SCALE;            // np.round = half-even
    float start_h = rintf(r2) * SCALE;
    float end_w   = rintf(r3 + 1.0f) * SCALE;
    float end_h   = rintf(r4 + 1.0f) * SCALE;
    float roi_w = fmaxf(end_w - start_w, 0.1f);
    float roi_h = fmaxf(end_h - start_h, 0.1f);
    const float inv7 = 1.0f / 7.0f;               // RN(1/7)
    g.bin_h = freeze(roi_h * inv7);               // reciprocal multiply
    g.bin_w = freeze(roi_w * inv7);
    g.start_h = start_h;
    g.start_w = start_w;
    return g;
}

__device__ __forceinline__ void bin_bounds(const RoiGeom& g, int ph, int pw,
                                           int& hs, int& he, int& ws, int& we) {
    float mh0 = freeze((float)ph * g.bin_h);      // separate mul, then add
    float mh1 = freeze((float)(ph + 1) * g.bin_h);
    float mw0 = freeze((float)pw * g.bin_w);
    float mw1 = freeze((float)(pw + 1) * g.bin_w);

    float hs_f = floorf(mh0 + g.start_h);
    float he_f = ceilf (mh1 + g.start_h);
    float ws_f = floorf(mw0 + g.start_w);
    float we_f = ceilf (mw1 + g.start_w);

    hs = (int)fminf(fmaxf(hs_f, 0.0f), (float)FH);
    he = (int)fminf(fmaxf(he_f, 0.0f), (float)FH);
    ws = (int)fminf(fmaxf(ws_f, 0.0f), (float)FW);
    we = (int)fminf(fmaxf(we_f, 0.0f), (float)FW);
}

// SAT-IN-LDS BIN-MAJOR (round 17). R1's skeleton (block=channel, 1024 thr,
// 64 KB LDS = 4 planes, 2 blocks/CU) was compute-bound: the divergent
// region sum costs ~30 issued lane-slots/wave (wave pays the max region of
// its 64 lanes) with dependent LDS-read+add chains ≈ ~20 of the ~31 us.
// R4/R5 proved batch-phased compute serializes 4x (256-wide phases on a
// 1024-lane machine). Fix the COMPUTE TERM instead: build per-plane SATs in
// LDS (the reference's own algorithm), then every region sum = 4 LDS reads
// + 3 adds, divergence-free. Build is wave-parallel shfl-scans: 256 rows +
// 256 cols over 16 waves.
//
// LDS swizzle (guide rule 21): column access at stride-64 floats is a
// 32-way bank conflict, so element (h,w) lives at float offset
// h*64 + (w ^ ((h&7)<<2)) — float4-granular XOR. Row pass stays
// conflict-free (bank = low5(w^s), bijective), col pass drops to 8-way.
// global_load_lds keeps a LINEAR LDS dest (hardware requirement, m104);
// the swizzle is applied by PRE-SWIZZLING the per-lane GLOBAL source
// address (j_src = j ^ (h&7), 16B-aligned since the XOR touches only
// float-bits 2..4). Every subsequent read applies the same XOR.
__global__ __launch_bounds__(1024)
void psroi_sat(const float* __restrict__ feat,
               const float* __restrict__ rois,
               float* __restrict__ ws) {
    const int c  = blockIdx.x;            // 0..1028  (== d*49 + ph*7 + pw)
    const int pw = c % 7;
    const int ph = (c / 7) % 7;
    const int t  = threadIdx.x;           // 0..1023 == ROI index
    const int ln = t & 63;
    const int wv = t >> 6;                // 0..15

    __shared__ float pl[4 * PLANE];       // 64 KB: 4 swizzled planes -> SATs

    // 1. ROI load first (in-order vmcnt retire: rr uses don't wait on the
    //    staging loads issued after them).
    const float* r = rois + (size_t)t * 5;
    float r0 = r[0], r1 = r[1], r2 = r[2], r3 = r[3], r4 = r[4];

    // 2. Stage 4 planes, source pre-swizzled, LDS dest linear (lane*16).
    const int sh = t >> 4;                // row this thread's float4 lands in
    const int sj = (t & 15) ^ (sh & 7);   // pre-swizzled float4 column
#if defined(__has_builtin) && __has_builtin(__builtin_amdgcn_global_load_lds)
    typedef const void __attribute__((address_space(1)))* gas_t;
    typedef void __attribute__((address_space(3)))*       las_t;
#pragma unroll
    for (int p = 0; p < 4; ++p) {
        const float* src = feat + ((size_t)p * CHANNELS + c) * PLANE
                         + (sh << 6) + (sj << 2);
        __builtin_amdgcn_global_load_lds((gas_t)src, (las_t)(pl + p * PLANE + 4 * t),
                                         16, 0, 0);
    }
#else
#pragma unroll
    for (int p = 0; p < 4; ++p) {
        const float4* s4 = reinterpret_cast<const float4*>(
            feat + ((size_t)p * CHANNELS + c) * PLANE);
        reinterpret_cast<float4*>(pl + p * PLANE)[t] = s4[(sh << 4) | sj];
    }
#endif

    // 3. Boundary chain overlaps the in-flight staging (registers only).
    RoiGeom g = roi_geom_v(r0, r1, r2, r3, r4);
    int hs, he, wss, wee;
    bin_bounds(g, ph, pw, hs, he, wss, wee);

    __syncthreads();                      // staging drained

    // 4. Row pass: inclusive shfl-scan along w. 256 rows / 16 waves.
    //    lane ln <-> column w=ln; addr bank = low5(ln ^ s) (conflict-free).
#pragma unroll 4
    for (int i = 0; i < 16; ++i) {
        const int gr = (wv << 4) | i;     // 0..255
        const int p  = gr >> 6;
        const int h  = gr & 63;
        const int ad = p * PLANE + (h << 6) + (ln ^ ((h & 7) << 2));
        float x = pl[ad];
#pragma unroll
        for (int d = 1; d < 64; d <<= 1) {
            float u = __shfl_up(x, d, 64);
            if (ln >= d) x += u;
        }
        pl[ad] = x;
    }
    __syncthreads();

    // 5. Col pass: inclusive shfl-scan along h. lane ln <-> row h=ln;
    //    bank = low5(w ^ ((ln&7)<<2)) -> 8 banks per col (8-way, ~2.9x).
#pragma unroll 4
    for (int i = 0; i < 16; ++i) {
        const int gc = (wv << 4) | i;     // 0..255
        const int p  = gc >> 6;
        const int w  = gc & 63;
        const int ad = p * PLANE + (ln << 6) + (w ^ ((ln & 7) << 2));
        float x = pl[ad];
#pragma unroll
        for (int d = 1; d < 64; d <<= 1) {
            float u = __shfl_up(x, d, 64);
            if (ln >= d) x += u;
        }
        pl[ad] = x;
    }
    __syncthreads();

    // 6. Extract: 4 swizzled SAT reads. Op order matches the reference's
    //    padded-SAT chain a - b - c + d (skipped terms are exact zeros).
    const float* base = pl + (g.b & 3) * PLANE;
#define SATV(h, w) base[((h) << 6) + ((w) ^ (((h) & 7) << 2))]
    const int area = (he - hs) * (wee - wss);
    float v = 0.0f;
    if (area > 0) {
        float s = SATV(he - 1, wee - 1);
        if (hs > 0)           s -= SATV(hs - 1, wee - 1);
        if (wss > 0)          s -= SATV(he - 1, wss - 1);
        if (hs > 0 && wss > 0) s += SATV(hs - 1, wss - 1);
        v = s / (float)area;
    }
#undef SATV
    ws[(size_t)c * NUM_ROIS + t] = v;     // coalesced 4 KB row
}

// ws[1029][1024] -> out[1024][1029]. 32x32 tiles, 256 threads, 33-pad LDS
// (conflict-free column reads). R1-verified byte-for-byte.
__global__ __launch_bounds__(256)
void transpose_cn(const float* __restrict__ ws, float* __restrict__ out) {
    __shared__ float tile[32][33];
    const int c0 = blockIdx.y * 32;
    const int n0 = blockIdx.x * 32;
    const int tx = threadIdx.x & 31;
    const int ty = threadIdx.x >> 5;              // 0..7

#pragma unroll
    for (int i = 0; i < 32; i += 8) {
        const int cc = c0 + ty + i;
        if (cc < CHANNELS)
            tile[ty + i][tx] = ws[(size_t)cc * NUM_ROIS + (n0 + tx)];
    }
    __syncthreads();
#pragma unroll
    for (int i = 0; i < 32; i += 8) {
        const int nn = n0 + ty + i;
        const int cc = c0 + tx;
        if (cc < CHANNELS)
            out[(size_t)nn * CHANNELS + cc] = tile[tx][ty + i];
    }
}

// ---------- fallback path (R1-verified, no workspace) ----------
__device__ __forceinline__ float region_avg(const float* __restrict__ plane,
                                            int hs, int he, int ws, int we) {
    float s = 0.0f;
    for (int h = hs; h < he; ++h) {
        const float* row = plane + h * FW;
        for (int w = ws; w < we; ++w) s += row[w];
    }
    int area = (he - hs) * (we - ws);
    return (area <= 0) ? 0.0f : s / (float)area;
}

__global__ __launch_bounds__(1024)
void psroi_lds_direct(const float* __restrict__ feat,
                      const float* __restrict__ rois,
                      float* __restrict__ dst) {
    const int c  = blockIdx.x;
    const int pw = c % 7;
    const int ph = (c / 7) % 7;
    const int t  = threadIdx.x;

    __shared__ float pl[4 * PLANE];

    const float* r = rois + (size_t)t * 5;
    float r0 = r[0], r1 = r[1], r2 = r[2], r3 = r[3], r4 = r[4];

#pragma unroll
    for (int bb = 0; bb < 4; ++bb) {
        const float4* src = reinterpret_cast<const float4*>(
            feat + ((size_t)bb * CHANNELS + c) * PLANE);
        reinterpret_cast<float4*>(pl + bb * PLANE)[t] = src[t];
    }

    RoiGeom g = roi_geom_v(r0, r1, r2, r3, r4);
    int hs, he, wss, wee;
    bin_bounds(g, ph, pw, hs, he, wss, wee);

    __syncthreads();

    float v = region_avg(pl + g.b * PLANE, hs, he, wss, wee);
    dst[(size_t)t * CHANNELS + c] = v;
}

extern "C" void kernel_launch(void* const* d_in, const int* in_sizes, int n_in,
                              void* d_out, int out_size, void* d_ws, size_t ws_size,
                              hipStream_t stream) {
    const float* feat = (const float*)d_in[0];
    const float* rois = (const float*)d_in[1];
    float* out = (float*)d_out;

    const size_t need = sizeof(float) * (size_t)CHANNELS * NUM_ROIS;
    if (d_ws != nullptr && ws_size >= need) {
        float* wsp = (float*)d_ws;
        psroi_sat<<<CHANNELS, 1024, 0, stream>>>(feat, rois, wsp);
        transpose_cn<<<dim3(NUM_ROIS / 32, (CHANNELS + 31) / 32), 256, 0, stream>>>(wsp, out);
    } else {
        psroi_lds_direct<<<CHANNELS, 1024, 0, stream>>>(feat, rois, out);
    }
}

// Round 7
// 98.325 us; speedup vs baseline: 1.4226x; 1.4226x over previous
//
#include <hip/hip_runtime.h>
#include <math.h>

#define POOLED      7
#define OUTPUT_DIM  21
#define GROUP       7
#define CHANNELS    (OUTPUT_DIM * GROUP * GROUP)   // 1029
#define FH          64
#define FW          64
#define PLANE       (FH * FW)                      // 4096 floats, 16 KB
#define NUM_ROIS    1024
#define SCALE       0.0625f
#define NBLK        256                            // persistent blocks, 1/CU

// Opaque VGPR pin: blocks FMA contraction (hipcc -ffp-contract=fast ignores
// `#pragma clang fp contract(off)`). CORRECTNESS-CRITICAL: the golden's
// boundary chain is f32, separately rounded, with bin = roi * RN(1/7)
// (reciprocal multiply) — verified round 10, absmax 3.9e-3. Do not change.
__device__ __forceinline__ float freeze(float x) {
    __asm__ volatile("" : "+v"(x));
    return x;
}

// ---- frozen boundary chain, value form (ops identical to r10-verified) ----
struct RoiGeom { int b; float start_h, start_w, bin_h, bin_w; };

__device__ __forceinline__ RoiGeom roi_geom_v(float r0, float r1, float r2,
                                              float r3, float r4) {
    RoiGeom g;
    g.b = (int)r0;
    float start_w = rintf(r1) * SCALE;            // np.round = half-even
    float start_h = rintf(r2) * SCALE;
    float end_w   = rintf(r3 + 1.0f) * SCALE;
    float end_h   = rintf(r4 + 1.0f) * SCALE;
    float roi_w = fmaxf(end_w - start_w, 0.1f);
    float roi_h = fmaxf(end_h - start_h, 0.1f);
    const float inv7 = 1.0f / 7.0f;               // RN(1/7)
    g.bin_h = freeze(roi_h * inv7);               // reciprocal multiply
    g.bin_w = freeze(roi_w * inv7);
    g.start_h = start_h;
    g.start_w = start_w;
    return g;
}

__device__ __forceinline__ void bin_bounds(const RoiGeom& g, int ph, int pw,
                                           int& hs, int& he, int& ws, int& we) {
    float mh0 = freeze((float)ph * g.bin_h);      // separate mul, then add
    float mh1 = freeze((float)(ph + 1) * g.bin_h);
    float mw0 = freeze((float)pw * g.bin_w);
    float mw1 = freeze((float)(pw + 1) * g.bin_w);

    float hs_f = floorf(mh0 + g.start_h);
    float he_f = ceilf (mh1 + g.start_h);
    float ws_f = floorf(mw0 + g.start_w);
    float we_f = ceilf (mw1 + g.start_w);

    hs = (int)fminf(fmaxf(hs_f, 0.0f), (float)FH);
    he = (int)fminf(fmaxf(he_f, 0.0f), (float)FH);
    ws = (int)fminf(fmaxf(ws_f, 0.0f), (float)FW);
    we = (int)fminf(fmaxf(we_f, 0.0f), (float)FW);
}

// Region sum — IDENTICAL op order to the R1-verified kernel (absmax 3.9e-3).
__device__ __forceinline__ float region_avg(const float* __restrict__ plane,
                                            int hs, int he, int ws, int we) {
    float s = 0.0f;
    for (int h = hs; h < he; ++h) {
        const float* row = plane + h * FW;
        for (int w = ws; w < we; ++w) s += row[w];
    }
    int area = (he - hs) * (we - ws);
    return (area <= 0) ? 0.0f : s / (float)area;
}

// PERSISTENT DOUBLE-BUFFERED BIN-MAJOR (round 18). History: R1/R3 (96.8/97.5)
// phase-lock stage->barrier->compute at 2 blocks/CU over 2 grid rounds ->
// main kernel ~20 us vs 10.7 us staging floor (compute itself ~1-2 us; R6's
// SAT detour proved compute is small). R4 (grid split) replicated the
// preamble 4116x; R5 (batch-phased dbuf) serialized compute 4x; R6 (SAT)
// swapped an ~11-iter data-parallel sum for 6-deep dependent shfl chains.
// All three regressed. This round overlaps WITHOUT those traps:
//   - 256 persistent blocks (1/CU), 1024 threads, LDS = 2 x 64 KB buffers
//     (gfx950 allows 160 KB/workgroup; 8-phase GEMM example uses 128 KB).
//   - Block owns channels c = bid, bid+256, ... (4-5 each, single round).
//   - Per channel (T3 minimal 2-phase recipe): STAGE4(next) fire-and-forget,
//     compute current from buf[cur] with ALL 1024 threads (1 ROI/thread,
//     no batch phasing), coalesced ws write, ONE barrier whose vmcnt-drain
//     doubles as "next buffer ready".
//   - ROI descriptor + RoiGeom loaded ONCE per block into registers; only
//     the ~20-VALU bin_bounds tail is per-channel.
// Staging of c+1 hides under compute+write of c; steady-state bound is the
// per-CU staging share (~2.7 us/channel), not stage+compute serial.
__global__ __launch_bounds__(1024)
void psroi_pipe(const float* __restrict__ feat,
                const float* __restrict__ rois,
                float* __restrict__ ws) {
    const int bid = blockIdx.x;           // 0..255
    const int t   = threadIdx.x;          // 0..1023 == ROI index

    __shared__ float buf[2][4 * PLANE];   // 2 x 64 KB

    // ROI load + geometry ONCE (registers; overlaps first staging).
    const float* r = rois + (size_t)t * 5;
    float r0 = r[0], r1 = r[1], r2 = r[2], r3 = r[3], r4 = r[4];

    // Stage one full plane per instruction: 1024 lanes x 16 B = 16 KB.
#if defined(__has_builtin) && __has_builtin(__builtin_amdgcn_global_load_lds)
    typedef const void __attribute__((address_space(1)))* gas_t;
    typedef void __attribute__((address_space(3)))*       las_t;
#define STAGE4(dst, ch)                                                         \
    do {                                                                        \
        _Pragma("unroll")                                                       \
        for (int p_ = 0; p_ < 4; ++p_) {                                        \
            const float* s_ = feat + ((size_t)p_ * CHANNELS + (ch)) * PLANE     \
                            + 4 * (size_t)t;                                    \
            __builtin_amdgcn_global_load_lds((gas_t)s_,                         \
                                             (las_t)((dst) + p_ * PLANE + 4 * t),\
                                             16, 0, 0);                         \
        }                                                                       \
    } while (0)
#else
#define STAGE4(dst, ch)                                                         \
    do {                                                                        \
        _Pragma("unroll")                                                       \
        for (int p_ = 0; p_ < 4; ++p_) {                                        \
            const float4* s4_ = reinterpret_cast<const float4*>(                \
                feat + ((size_t)p_ * CHANNELS + (ch)) * PLANE);                 \
            reinterpret_cast<float4*>((dst) + p_ * PLANE)[t] = s4_[t];          \
        }                                                                       \
    } while (0)
#endif

    int c = bid;
    STAGE4(buf[0], c);

    const RoiGeom g = roi_geom_v(r0, r1, r2, r3, r4);
    const float* myplane0 = buf[0] + g.b * PLANE;   // per-lane base, buffer 0
    const float* myplane1 = buf[1] + g.b * PLANE;

    __syncthreads();                      // drains vmcnt -> buf[0] ready

    int cur = 0;
    for (;;) {
        const int cn = c + NBLK;
        if (cn < CHANNELS) STAGE4(buf[cur ^ 1], cn);   // fly under compute

        const int pw = c % 7;
        const int ph = (c / 7) % 7;
        int hs, he, wss, wee;
        bin_bounds(g, ph, pw, hs, he, wss, wee);

        float v = region_avg(cur ? myplane1 : myplane0, hs, he, wss, wee);
        ws[(size_t)c * NUM_ROIS + t] = v;            // coalesced 4 KB row

        if (cn >= CHANNELS) break;
        __syncthreads();   // cur reads done + stage(cn) drained (vmcnt(0))
        cur ^= 1;
        c = cn;
    }
#undef STAGE4
}

// ws[1029][1024] -> out[1024][1029]. 32x32 tiles, 256 threads, 33-pad LDS
// (conflict-free column reads). R1-verified byte-for-byte.
__global__ __launch_bounds__(256)
void transpose_cn(const float* __restrict__ ws, float* __restrict__ out) {
    __shared__ float tile[32][33];
    const int c0 = blockIdx.y * 32;
    const int n0 = blockIdx.x * 32;
    const int tx = threadIdx.x & 31;
    const int ty = threadIdx.x >> 5;              // 0..7

#pragma unroll
    for (int i = 0; i < 32; i += 8) {
        const int cc = c0 + ty + i;
        if (cc < CHANNELS)
            tile[ty + i][tx] = ws[(size_t)cc * NUM_ROIS + (n0 + tx)];
    }
    __syncthreads();
#pragma unroll
    for (int i = 0; i < 32; i += 8) {
        const int nn = n0 + ty + i;
        const int cc = c0 + tx;
        if (cc < CHANNELS)
            out[(size_t)nn * CHANNELS + cc] = tile[tx][ty + i];
    }
}

// ---------- fallback path (R1-verified, no workspace) ----------
__global__ __launch_bounds__(1024)
void psroi_lds_direct(const float* __restrict__ feat,
                      const float* __restrict__ rois,
                      float* __restrict__ dst) {
    const int c  = blockIdx.x;
    const int pw = c % 7;
    const int ph = (c / 7) % 7;
    const int t  = threadIdx.x;

    __shared__ float pl[4 * PLANE];

    const float* r = rois + (size_t)t * 5;
    float r0 = r[0], r1 = r[1], r2 = r[2], r3 = r[3], r4 = r[4];

#pragma unroll
    for (int bb = 0; bb < 4; ++bb) {
        const float4* src = reinterpret_cast<const float4*>(
            feat + ((size_t)bb * CHANNELS + c) * PLANE);
        reinterpret_cast<float4*>(pl + bb * PLANE)[t] = src[t];
    }

    RoiGeom g = roi_geom_v(r0, r1, r2, r3, r4);
    int hs, he, wss, wee;
    bin_bounds(g, ph, pw, hs, he, wss, wee);

    __syncthreads();

    float v = region_avg(pl + g.b * PLANE, hs, he, wss, wee);
    dst[(size_t)t * CHANNELS + c] = v;
}

extern "C" void kernel_launch(void* const* d_in, const int* in_sizes, int n_in,
                              void* d_out, int out_size, void* d_ws, size_t ws_size,
                              hipStream_t stream) {
    const float* feat = (const float*)d_in[0];
    const float* rois = (const float*)d_in[1];
    float* out = (float*)d_out;

    const size_t need = sizeof(float) * (size_t)CHANNELS * NUM_ROIS;
    if (d_ws != nullptr && ws_size >= need) {
        float* wsp = (float*)d_ws;
        psroi_pipe<<<NBLK, 1024, 0, stream>>>(feat, rois, wsp);
        transpose_cn<<<dim3(NUM_ROIS / 32, (CHANNELS + 31) / 32), 256, 0, stream>>>(wsp, out);
    } else {
        psroi_lds_direct<<<CHANNELS, 1024, 0, stream>>>(feat, rois, out);
    }
}